// Round 1
// baseline (185.273 us; speedup 1.0000x reference)
//
#include <hip/hip_runtime.h>

// LTC cell fused kernel. B=512, S=256, N=256, 6 unfolds.
// Strategy: precompute packed params {sigma*log2e, sigma*mu*log2e, w, w*erev}
// so each sigmoid is: t = exp2(B - A*x); s = rcp(1+t); den += w*s; num += werev*s.
// Main kernel: 1 block per 2 batch rows (grid=256, block=1024 = 256 cols x 4 i-chunks).
// v lives in LDS across all 6 unfolds (rows independent -> no grid sync).

#define LOG2E 1.4426950408889634f

constexpr int Bb = 512;
constexpr int Ss = 256;
constexpr int Nn = 256;
constexpr int UNFOLDS = 6;
constexpr float EPS = 1e-8f;

__global__ __launch_bounds__(256) void pack_kernel(
    const float* __restrict__ sigma, const float* __restrict__ mu,
    const float* __restrict__ w, const float* __restrict__ erev,
    const float* __restrict__ ssigma, const float* __restrict__ smu,
    const float* __restrict__ sw, const float* __restrict__ serev,
    float4* __restrict__ packed, float4* __restrict__ spacked) {
  int idx = blockIdx.x * blockDim.x + threadIdx.x;  // 0..65535 (N*N == S*N)
  {
    float sg = sigma[idx] * LOG2E;
    float ww = w[idx];
    packed[idx] = make_float4(sg, sg * mu[idx], ww, ww * erev[idx]);
  }
  {
    float sg = ssigma[idx] * LOG2E;
    float ww = sw[idx];
    spacked[idx] = make_float4(sg, sg * smu[idx], ww, ww * serev[idx]);
  }
}

template <bool PACKED>
__global__ __launch_bounds__(1024) void ltc_kernel(
    const float* __restrict__ input, const float* __restrict__ hx,
    const float* __restrict__ ts, const float* __restrict__ gleak,
    const float* __restrict__ vleak, const float* __restrict__ cm,
    const float* __restrict__ input_w, const float* __restrict__ input_b,
    const float4* __restrict__ packed, const float4* __restrict__ spacked,
    const float* __restrict__ sigmaP, const float* __restrict__ muP,
    const float* __restrict__ wP, const float* __restrict__ erevP,
    const float* __restrict__ ssigmaP, const float* __restrict__ smuP,
    const float* __restrict__ swP, const float* __restrict__ serevP,
    float* __restrict__ out) {
  __shared__ alignas(16) float v_lds[2][Nn];
  __shared__ alignas(16) float inp_lds[2][Ss];
  __shared__ alignas(16) float4 red[1024];  // 16 KB

  const int tid = threadIdx.x;
  const int j = tid & 255;   // output column
  const int c = tid >> 8;    // i-chunk 0..3 (wave-uniform)
  const int b0 = blockIdx.x * 2;

  // Stage inputs (with input_w/input_b affine) and hx into LDS.
  if (tid < 512) {
    int r = tid >> 8, s = tid & 255;
    inp_lds[r][s] = input[(b0 + r) * Ss + s] * input_w[s] + input_b[s];
    v_lds[r][s] = hx[(b0 + r) * Nn + s];
  }
  __syncthreads();

  // ---- sensory pass: accumulate per-chunk partial sums over s ----
  float sn0 = 0.f, sd0 = 0.f, sn1 = 0.f, sd1 = 0.f;
  {
    const int i0 = c * 64;
#pragma unroll 4
    for (int i4 = i0; i4 < i0 + 64; i4 += 4) {
      float4 xa = *(const float4*)&inp_lds[0][i4];
      float4 xb = *(const float4*)&inp_lds[1][i4];
#pragma unroll
      for (int u = 0; u < 4; ++u) {
        int i = i4 + u;
        float px, py, pz, pw;
        if constexpr (PACKED) {
          float4 p = spacked[i * Nn + j];
          px = p.x; py = p.y; pz = p.z; pw = p.w;
        } else {
          int idx = i * Nn + j;
          px = ssigmaP[idx] * LOG2E;
          py = px * smuP[idx];
          pz = swP[idx];
          pw = pz * serevP[idx];
        }
        float x0 = (u == 0) ? xa.x : (u == 1) ? xa.y : (u == 2) ? xa.z : xa.w;
        float x1 = (u == 0) ? xb.x : (u == 1) ? xb.y : (u == 2) ? xb.z : xb.w;
        float t0 = __builtin_exp2f(py - px * x0);
        float t1 = __builtin_exp2f(py - px * x1);
        float s0 = __builtin_amdgcn_rcpf(1.f + t0);
        float s1 = __builtin_amdgcn_rcpf(1.f + t1);
        sd0 += pz * s0;
        sn0 += pw * s0;
        sd1 += pz * s1;
        sn1 += pw * s1;
      }
    }
  }
  red[tid] = make_float4(sn0, sd0, sn1, sd1);
  __syncthreads();

  float snum0 = 0.f, sden0 = 0.f, snum1 = 0.f, sden1 = 0.f;
  float cmt0 = 0.f, cmt1 = 0.f, glj = 0.f, glvl = 0.f;
  if (c == 0) {
    float4 a = red[j], b = red[256 + j], cc = red[512 + j], d = red[768 + j];
    snum0 = a.x + b.x + cc.x + d.x;
    sden0 = a.y + b.y + cc.y + d.y;
    snum1 = a.z + b.z + cc.z + d.z;
    sden1 = a.w + b.w + cc.w + d.w;
    glj = gleak[j];
    glvl = glj * vleak[j];
    float cmj = cm[j];
    cmt0 = cmj / ((ts[b0] + 1.f) / (float)UNFOLDS);
    cmt1 = cmj / ((ts[b0 + 1] + 1.f) / (float)UNFOLDS);
  }
  __syncthreads();  // protect red[] before step-loop rewrites it

  // ---- 6 ODE unfolds, v resident in LDS ----
  float vo0 = 0.f, vo1 = 0.f;
  for (int step = 0; step < UNFOLDS; ++step) {
    float n0 = 0.f, d0 = 0.f, n1 = 0.f, d1 = 0.f;
    const int i0 = c * 64;
#pragma unroll 4
    for (int i4 = i0; i4 < i0 + 64; i4 += 4) {
      float4 va = *(const float4*)&v_lds[0][i4];
      float4 vb = *(const float4*)&v_lds[1][i4];
#pragma unroll
      for (int u = 0; u < 4; ++u) {
        int i = i4 + u;
        float px, py, pz, pw;
        if constexpr (PACKED) {
          float4 p = packed[i * Nn + j];
          px = p.x; py = p.y; pz = p.z; pw = p.w;
        } else {
          int idx = i * Nn + j;
          px = sigmaP[idx] * LOG2E;
          py = px * muP[idx];
          pz = wP[idx];
          pw = pz * erevP[idx];
        }
        float x0 = (u == 0) ? va.x : (u == 1) ? va.y : (u == 2) ? va.z : va.w;
        float x1 = (u == 0) ? vb.x : (u == 1) ? vb.y : (u == 2) ? vb.z : vb.w;
        float t0 = __builtin_exp2f(py - px * x0);
        float t1 = __builtin_exp2f(py - px * x1);
        float s0 = __builtin_amdgcn_rcpf(1.f + t0);
        float s1 = __builtin_amdgcn_rcpf(1.f + t1);
        d0 += pz * s0;
        n0 += pw * s0;
        d1 += pz * s1;
        n1 += pw * s1;
      }
    }
    red[tid] = make_float4(n0, d0, n1, d1);
    __syncthreads();
    if (c == 0) {
      float4 a = red[j], b = red[256 + j], cc = red[512 + j], d = red[768 + j];
      float num0 = a.x + b.x + cc.x + d.x + snum0;
      float den0 = a.y + b.y + cc.y + d.y + sden0;
      float num1 = a.z + b.z + cc.z + d.z + snum1;
      float den1 = a.w + b.w + cc.w + d.w + sden1;
      float v0 = v_lds[0][j], v1 = v_lds[1][j];
      vo0 = (cmt0 * v0 + glvl + num0) / (cmt0 + glj + den0 + EPS);
      vo1 = (cmt1 * v1 + glvl + num1) / (cmt1 + glj + den1 + EPS);
      v_lds[0][j] = vo0;
      v_lds[1][j] = vo1;
    }
    __syncthreads();
  }

  if (c == 0) {
    out[b0 * Nn + j] = vo0;
    out[(b0 + 1) * Nn + j] = vo1;
  }
}

extern "C" void kernel_launch(void* const* d_in, const int* in_sizes, int n_in,
                              void* d_out, int out_size, void* d_ws, size_t ws_size,
                              hipStream_t stream) {
  const float* input   = (const float*)d_in[0];
  const float* hx      = (const float*)d_in[1];
  const float* ts      = (const float*)d_in[2];
  const float* gleak   = (const float*)d_in[3];
  const float* vleak   = (const float*)d_in[4];
  const float* cm      = (const float*)d_in[5];
  const float* sigma   = (const float*)d_in[6];
  const float* mu      = (const float*)d_in[7];
  const float* w       = (const float*)d_in[8];
  const float* erev    = (const float*)d_in[9];
  const float* ssigma  = (const float*)d_in[10];
  const float* smu     = (const float*)d_in[11];
  const float* sw      = (const float*)d_in[12];
  const float* serev   = (const float*)d_in[13];
  const float* input_w = (const float*)d_in[14];
  const float* input_b = (const float*)d_in[15];
  float* out = (float*)d_out;

  const size_t need = (size_t)2 * Nn * Nn * sizeof(float4);  // 2 MB
  if (ws_size >= need) {
    float4* packed = (float4*)d_ws;
    float4* spacked = packed + Nn * Nn;
    pack_kernel<<<Nn * Nn / 256, 256, 0, stream>>>(sigma, mu, w, erev, ssigma, smu,
                                                   sw, serev, packed, spacked);
    ltc_kernel<true><<<Bb / 2, 1024, 0, stream>>>(
        input, hx, ts, gleak, vleak, cm, input_w, input_b, packed, spacked,
        sigma, mu, w, erev, ssigma, smu, sw, serev, out);
  } else {
    ltc_kernel<false><<<Bb / 2, 1024, 0, stream>>>(
        input, hx, ts, gleak, vleak, cm, input_w, input_b, nullptr, nullptr,
        sigma, mu, w, erev, ssigma, smu, sw, serev, out);
  }
}

// Round 3
// 158.467 us; speedup vs baseline: 1.1692x; 1.1692x over previous
//
#include <hip/hip_runtime.h>

// LTC cell fused kernel. B=512, S=256, N=256, 6 unfolds.
// R2 changes vs R1 (resubmitted in R3 after broker timeout):
//  - raw v_exp_f32 via __builtin_amdgcn_exp2f (R1 used __builtin_exp2f, which
//    lowers with a denormal-range fixup sequence: ~2x VALU per sigmoid)
//  - 12B packed params {A=sigma*log2e, A*mu, w*erev}; erev=+-1 so w=|w*erev|
//    recovered with the free abs input-modifier on the accumulating FMA.
//    Cuts the per-step L2 param stream 16B->12B per element.

#define LOG2E 1.4426950408889634f

#if __has_builtin(__builtin_amdgcn_exp2f)
#define EXP2_RAW(x) __builtin_amdgcn_exp2f(x)
#else
#define EXP2_RAW(x) __builtin_exp2f(x)
#endif
#if __has_builtin(__builtin_amdgcn_rcpf)
#define RCP_RAW(x) __builtin_amdgcn_rcpf(x)
#else
#define RCP_RAW(x) (1.0f / (x))
#endif

constexpr int Bb = 512;
constexpr int Ss = 256;
constexpr int Nn = 256;
constexpr int UNFOLDS = 6;
constexpr float EPS = 1e-8f;

struct P12 {
  float a;   // sigma * log2e
  float am;  // sigma * log2e * mu
  float ws;  // w * erev  (erev = +-1, so w = fabs(ws))
};

__global__ __launch_bounds__(256) void pack_kernel(
    const float* __restrict__ sigma, const float* __restrict__ mu,
    const float* __restrict__ w, const float* __restrict__ erev,
    const float* __restrict__ ssigma, const float* __restrict__ smu,
    const float* __restrict__ sw, const float* __restrict__ serev,
    P12* __restrict__ packed, P12* __restrict__ spacked) {
  int idx = blockIdx.x * blockDim.x + threadIdx.x;  // 0..65535 (N*N == S*N)
  {
    float sg = sigma[idx] * LOG2E;
    P12 p;
    p.a = sg;
    p.am = sg * mu[idx];
    p.ws = w[idx] * erev[idx];
    packed[idx] = p;
  }
  {
    float sg = ssigma[idx] * LOG2E;
    P12 p;
    p.a = sg;
    p.am = sg * smu[idx];
    p.ws = sw[idx] * serev[idx];
    spacked[idx] = p;
  }
}

template <bool PACKED>
__global__ __launch_bounds__(1024) void ltc_kernel(
    const float* __restrict__ input, const float* __restrict__ hx,
    const float* __restrict__ ts, const float* __restrict__ gleak,
    const float* __restrict__ vleak, const float* __restrict__ cm,
    const float* __restrict__ input_w, const float* __restrict__ input_b,
    const P12* __restrict__ packed, const P12* __restrict__ spacked,
    const float* __restrict__ sigmaP, const float* __restrict__ muP,
    const float* __restrict__ wP, const float* __restrict__ erevP,
    const float* __restrict__ ssigmaP, const float* __restrict__ smuP,
    const float* __restrict__ swP, const float* __restrict__ serevP,
    float* __restrict__ out) {
  __shared__ alignas(16) float v_lds[2][Nn];
  __shared__ alignas(16) float inp_lds[2][Ss];
  __shared__ alignas(16) float4 red[1024];  // 16 KB

  const int tid = threadIdx.x;
  const int j = tid & 255;   // output column
  const int c = tid >> 8;    // i-chunk 0..3 (wave-uniform)
  const int b0 = blockIdx.x * 2;

  // Stage inputs (with input_w/input_b affine) and hx into LDS.
  if (tid < 512) {
    int r = tid >> 8, s = tid & 255;
    inp_lds[r][s] = input[(b0 + r) * Ss + s] * input_w[s] + input_b[s];
    v_lds[r][s] = hx[(b0 + r) * Nn + s];
  }
  __syncthreads();

  // ---- sensory pass: accumulate per-chunk partial sums over s ----
  float sn0 = 0.f, sd0 = 0.f, sn1 = 0.f, sd1 = 0.f;
  {
    const int i0 = c * 64;
#pragma unroll 4
    for (int i4 = i0; i4 < i0 + 64; i4 += 4) {
      float4 xa = *(const float4*)&inp_lds[0][i4];
      float4 xb = *(const float4*)&inp_lds[1][i4];
#pragma unroll
      for (int u = 0; u < 4; ++u) {
        int i = i4 + u;
        float px, py, pw;
        if constexpr (PACKED) {
          P12 p = spacked[i * Nn + j];
          px = p.a; py = p.am; pw = p.ws;
        } else {
          int idx = i * Nn + j;
          px = ssigmaP[idx] * LOG2E;
          py = px * smuP[idx];
          pw = swP[idx] * serevP[idx];
        }
        float x0 = (u == 0) ? xa.x : (u == 1) ? xa.y : (u == 2) ? xa.z : xa.w;
        float x1 = (u == 0) ? xb.x : (u == 1) ? xb.y : (u == 2) ? xb.z : xb.w;
        float t0 = EXP2_RAW(py - px * x0);
        float t1 = EXP2_RAW(py - px * x1);
        float s0 = RCP_RAW(1.f + t0);
        float s1 = RCP_RAW(1.f + t1);
        sd0 += __builtin_fabsf(pw) * s0;  // abs folds into FMA input modifier
        sn0 += pw * s0;
        sd1 += __builtin_fabsf(pw) * s1;
        sn1 += pw * s1;
      }
    }
  }
  red[tid] = make_float4(sn0, sd0, sn1, sd1);
  __syncthreads();

  float snum0 = 0.f, sden0 = 0.f, snum1 = 0.f, sden1 = 0.f;
  float cmt0 = 0.f, cmt1 = 0.f, glj = 0.f, glvl = 0.f;
  if (c == 0) {
    float4 a = red[j], b = red[256 + j], cc = red[512 + j], d = red[768 + j];
    snum0 = a.x + b.x + cc.x + d.x;
    sden0 = a.y + b.y + cc.y + d.y;
    snum1 = a.z + b.z + cc.z + d.z;
    sden1 = a.w + b.w + cc.w + d.w;
    glj = gleak[j];
    glvl = glj * vleak[j];
    float cmj = cm[j];
    cmt0 = cmj / ((ts[b0] + 1.f) / (float)UNFOLDS);
    cmt1 = cmj / ((ts[b0 + 1] + 1.f) / (float)UNFOLDS);
  }
  __syncthreads();  // protect red[] before step-loop rewrites it

  // ---- 6 ODE unfolds, v resident in LDS ----
  float vo0 = 0.f, vo1 = 0.f;
  for (int step = 0; step < UNFOLDS; ++step) {
    float n0 = 0.f, d0 = 0.f, n1 = 0.f, d1 = 0.f;
    const int i0 = c * 64;
#pragma unroll 4
    for (int i4 = i0; i4 < i0 + 64; i4 += 4) {
      float4 va = *(const float4*)&v_lds[0][i4];
      float4 vb = *(const float4*)&v_lds[1][i4];
#pragma unroll
      for (int u = 0; u < 4; ++u) {
        int i = i4 + u;
        float px, py, pw;
        if constexpr (PACKED) {
          P12 p = packed[i * Nn + j];
          px = p.a; py = p.am; pw = p.ws;
        } else {
          int idx = i * Nn + j;
          px = sigmaP[idx] * LOG2E;
          py = px * muP[idx];
          pw = wP[idx] * erevP[idx];
        }
        float x0 = (u == 0) ? va.x : (u == 1) ? va.y : (u == 2) ? va.z : va.w;
        float x1 = (u == 0) ? vb.x : (u == 1) ? vb.y : (u == 2) ? vb.z : vb.w;
        float t0 = EXP2_RAW(py - px * x0);
        float t1 = EXP2_RAW(py - px * x1);
        float s0 = RCP_RAW(1.f + t0);
        float s1 = RCP_RAW(1.f + t1);
        d0 += __builtin_fabsf(pw) * s0;
        n0 += pw * s0;
        d1 += __builtin_fabsf(pw) * s1;
        n1 += pw * s1;
      }
    }
    red[tid] = make_float4(n0, d0, n1, d1);
    __syncthreads();
    if (c == 0) {
      float4 a = red[j], b = red[256 + j], cc = red[512 + j], d = red[768 + j];
      float num0 = a.x + b.x + cc.x + d.x + snum0;
      float den0 = a.y + b.y + cc.y + d.y + sden0;
      float num1 = a.z + b.z + cc.z + d.z + snum1;
      float den1 = a.w + b.w + cc.w + d.w + sden1;
      float v0 = v_lds[0][j], v1 = v_lds[1][j];
      vo0 = (cmt0 * v0 + glvl + num0) / (cmt0 + glj + den0 + EPS);
      vo1 = (cmt1 * v1 + glvl + num1) / (cmt1 + glj + den1 + EPS);
      v_lds[0][j] = vo0;
      v_lds[1][j] = vo1;
    }
    __syncthreads();
  }

  if (c == 0) {
    out[b0 * Nn + j] = vo0;
    out[(b0 + 1) * Nn + j] = vo1;
  }
}

extern "C" void kernel_launch(void* const* d_in, const int* in_sizes, int n_in,
                              void* d_out, int out_size, void* d_ws, size_t ws_size,
                              hipStream_t stream) {
  const float* input   = (const float*)d_in[0];
  const float* hx      = (const float*)d_in[1];
  const float* ts      = (const float*)d_in[2];
  const float* gleak   = (const float*)d_in[3];
  const float* vleak   = (const float*)d_in[4];
  const float* cm      = (const float*)d_in[5];
  const float* sigma   = (const float*)d_in[6];
  const float* mu      = (const float*)d_in[7];
  const float* w       = (const float*)d_in[8];
  const float* erev    = (const float*)d_in[9];
  const float* ssigma  = (const float*)d_in[10];
  const float* smu     = (const float*)d_in[11];
  const float* sw      = (const float*)d_in[12];
  const float* serev   = (const float*)d_in[13];
  const float* input_w = (const float*)d_in[14];
  const float* input_b = (const float*)d_in[15];
  float* out = (float*)d_out;

  const size_t need = (size_t)2 * Nn * Nn * sizeof(P12);  // 1.5 MB
  if (ws_size >= need) {
    P12* packed = (P12*)d_ws;
    P12* spacked = packed + Nn * Nn;
    pack_kernel<<<Nn * Nn / 256, 256, 0, stream>>>(sigma, mu, w, erev, ssigma, smu,
                                                   sw, serev, packed, spacked);
    ltc_kernel<true><<<Bb / 2, 1024, 0, stream>>>(
        input, hx, ts, gleak, vleak, cm, input_w, input_b, packed, spacked,
        sigma, mu, w, erev, ssigma, smu, sw, serev, out);
  } else {
    ltc_kernel<false><<<Bb / 2, 1024, 0, stream>>>(
        input, hx, ts, gleak, vleak, cm, input_w, input_b, nullptr, nullptr,
        sigma, mu, w, erev, ssigma, smu, sw, serev, out);
  }
}

// Round 4
// 147.876 us; speedup vs baseline: 1.2529x; 1.0716x over previous
//
#include <hip/hip_runtime.h>

// LTC cell fused kernel. B=512, S=256, N=256, 6 unfolds.
// R4 vs R3:
//  - quad-plane packed params: 3 float4 planes per table (a4, am4, ws4),
//    indexed [iq*256 + j]; 3 coalesced dwordx4 loads per 8 sigmoids.
//  - explicit next-quad register prefetch (unroll-2 rotation) to hide the
//    ~200-300cy L2 latency that R3 (VGPR=64, no pipelining) ate per i4-block.
//  - __launch_bounds__(1024,1): allow up to 128 VGPR (4 waves/SIMD fixed).
//  - ext_vector float2 math across i-pairs (v_pk_fma_f32 upside, no downside).
//  - |w| hoisted per quad (shared across both rows).

#define LOG2E 1.4426950408889634f
#define EXP2_RAW(x) __builtin_amdgcn_exp2f(x)
#define RCP_RAW(x) __builtin_amdgcn_rcpf(x)

typedef float f2 __attribute__((ext_vector_type(2)));

constexpr int Bb = 512;
constexpr int Ss = 256;
constexpr int Nn = 256;
constexpr int UNFOLDS = 6;
constexpr float EPS = 1e-8f;
// plane: 64 quads x 256 cols of float4 = 16384 float4 = 256 KB

__global__ __launch_bounds__(256) void pack_kernel(
    const float* __restrict__ sg, const float* __restrict__ mu,
    const float* __restrict__ w, const float* __restrict__ er,
    const float* __restrict__ ssg, const float* __restrict__ smu,
    const float* __restrict__ sw, const float* __restrict__ ser,
    float4* __restrict__ pa, float4* __restrict__ pam, float4* __restrict__ pws,
    float4* __restrict__ sa, float4* __restrict__ sam, float4* __restrict__ sws) {
  int idx = blockIdx.x * 256 + threadIdx.x;  // iq*256 + j, 16384 total
  int b = (idx >> 8) * 4 * Nn + (idx & 255); // row (4*iq), col j
  {
    float a0 = sg[b] * LOG2E, a1 = sg[b + 256] * LOG2E;
    float a2 = sg[b + 512] * LOG2E, a3 = sg[b + 768] * LOG2E;
    pa[idx] = make_float4(a0, a1, a2, a3);
    pam[idx] = make_float4(a0 * mu[b], a1 * mu[b + 256], a2 * mu[b + 512], a3 * mu[b + 768]);
    pws[idx] = make_float4(w[b] * er[b], w[b + 256] * er[b + 256],
                           w[b + 512] * er[b + 512], w[b + 768] * er[b + 768]);
  }
  {
    float a0 = ssg[b] * LOG2E, a1 = ssg[b + 256] * LOG2E;
    float a2 = ssg[b + 512] * LOG2E, a3 = ssg[b + 768] * LOG2E;
    sa[idx] = make_float4(a0, a1, a2, a3);
    sam[idx] = make_float4(a0 * smu[b], a1 * smu[b + 256], a2 * smu[b + 512], a3 * smu[b + 768]);
    sws[idx] = make_float4(sw[b] * ser[b], sw[b + 256] * ser[b + 256],
                           sw[b + 512] * ser[b + 512], sw[b + 768] * ser[b + 768]);
  }
}

struct Acc8 {
  f2 na0, nb0, da0, db0, na1, nb1, da1, db1;
};

// One full contraction pass (64 i-values for chunk c, 2 rows) with
// register-double-buffered param prefetch.
template <bool PACKED>
__device__ __forceinline__ Acc8 pass_accum(
    const float4* __restrict__ pa, const float4* __restrict__ pam,
    const float4* __restrict__ pws,
    const float* __restrict__ rS, const float* __restrict__ rM,
    const float* __restrict__ rW, const float* __restrict__ rE,
    const float* x0p, const float* x1p, int c, int j) {
  Acc8 acc;
  acc.na0 = 0.f; acc.nb0 = 0.f; acc.da0 = 0.f; acc.db0 = 0.f;
  acc.na1 = 0.f; acc.nb1 = 0.f; acc.da1 = 0.f; acc.db1 = 0.f;
  const int pb0 = c * 4096 + j;
  float4 A, M, W;
  if constexpr (PACKED) { A = pa[pb0]; M = pam[pb0]; W = pws[pb0]; }
#pragma unroll 2
  for (int ip = 0; ip < 16; ++ip) {
    float4 An, Mn, Wn;
    if constexpr (PACKED) {
      // prefetch NEXT quad's params (wraps on last iter; harmless reload)
      const int ni = pb0 + (((ip + 1) & 15) << 8);
      An = pa[ni]; Mn = pam[ni]; Wn = pws[ni];
    } else {
      const int b = (c * 64 + ip * 4) * Nn + j;
      A.x = rS[b] * LOG2E; A.y = rS[b + 256] * LOG2E;
      A.z = rS[b + 512] * LOG2E; A.w = rS[b + 768] * LOG2E;
      M.x = A.x * rM[b]; M.y = A.y * rM[b + 256];
      M.z = A.z * rM[b + 512]; M.w = A.w * rM[b + 768];
      W.x = rW[b] * rE[b]; W.y = rW[b + 256] * rE[b + 256];
      W.z = rW[b + 512] * rE[b + 512]; W.w = rW[b + 768] * rE[b + 768];
    }
    const int ib = c * 64 + ip * 4;
    const float4 xq0 = *reinterpret_cast<const float4*>(&x0p[ib]);
    const float4 xq1 = *reinterpret_cast<const float4*>(&x1p[ib]);

    const f2 a01 = {A.x, A.y}, a23 = {A.z, A.w};
    const f2 m01 = {M.x, M.y}, m23 = {M.z, M.w};
    const f2 wn01 = {W.x, W.y}, wn23 = {W.z, W.w};
    const f2 wd01 = {__builtin_fabsf(W.x), __builtin_fabsf(W.y)};
    const f2 wd23 = {__builtin_fabsf(W.z), __builtin_fabsf(W.w)};

    {  // row 0
      const f2 x01 = {xq0.x, xq0.y}, x23 = {xq0.z, xq0.w};
      const f2 y01 = m01 - a01 * x01;
      const f2 y23 = m23 - a23 * x23;
      f2 t01, t23, s01, s23;
      t01.x = EXP2_RAW(y01.x); t01.y = EXP2_RAW(y01.y);
      t23.x = EXP2_RAW(y23.x); t23.y = EXP2_RAW(y23.y);
      const f2 u01 = t01 + 1.0f, u23 = t23 + 1.0f;
      s01.x = RCP_RAW(u01.x); s01.y = RCP_RAW(u01.y);
      s23.x = RCP_RAW(u23.x); s23.y = RCP_RAW(u23.y);
      acc.na0 += wn01 * s01; acc.nb0 += wn23 * s23;
      acc.da0 += wd01 * s01; acc.db0 += wd23 * s23;
    }
    {  // row 1
      const f2 x01 = {xq1.x, xq1.y}, x23 = {xq1.z, xq1.w};
      const f2 y01 = m01 - a01 * x01;
      const f2 y23 = m23 - a23 * x23;
      f2 t01, t23, s01, s23;
      t01.x = EXP2_RAW(y01.x); t01.y = EXP2_RAW(y01.y);
      t23.x = EXP2_RAW(y23.x); t23.y = EXP2_RAW(y23.y);
      const f2 u01 = t01 + 1.0f, u23 = t23 + 1.0f;
      s01.x = RCP_RAW(u01.x); s01.y = RCP_RAW(u01.y);
      s23.x = RCP_RAW(u23.x); s23.y = RCP_RAW(u23.y);
      acc.na1 += wn01 * s01; acc.nb1 += wn23 * s23;
      acc.da1 += wd01 * s01; acc.db1 += wd23 * s23;
    }
    if constexpr (PACKED) { A = An; M = Mn; W = Wn; }
  }
  return acc;
}

template <bool PACKED>
__global__ __launch_bounds__(1024, 1) void ltc_kernel(
    const float* __restrict__ input, const float* __restrict__ hx,
    const float* __restrict__ ts, const float* __restrict__ gleak,
    const float* __restrict__ vleak, const float* __restrict__ cm,
    const float* __restrict__ input_w, const float* __restrict__ input_b,
    const float4* __restrict__ pa, const float4* __restrict__ pam,
    const float4* __restrict__ pws, const float4* __restrict__ sa,
    const float4* __restrict__ sam, const float4* __restrict__ sws,
    const float* __restrict__ sigmaP, const float* __restrict__ muP,
    const float* __restrict__ wP, const float* __restrict__ erevP,
    const float* __restrict__ ssigmaP, const float* __restrict__ smuP,
    const float* __restrict__ swP, const float* __restrict__ serevP,
    float* __restrict__ out) {
  __shared__ alignas(16) float v_lds[2][Nn];
  __shared__ alignas(16) float inp_lds[2][Ss];
  __shared__ alignas(16) float4 red[1024];  // 16 KB

  const int tid = threadIdx.x;
  const int j = tid & 255;   // output column
  const int c = tid >> 8;    // i-chunk 0..3 (wave-uniform)
  const int b0 = blockIdx.x * 2;

  if (tid < 512) {
    int r = tid >> 8, s = tid & 255;
    inp_lds[r][s] = input[(b0 + r) * Ss + s] * input_w[s] + input_b[s];
    v_lds[r][s] = hx[(b0 + r) * Nn + s];
  }
  __syncthreads();

  // ---- sensory pass ----
  {
    Acc8 acc = pass_accum<PACKED>(sa, sam, sws, ssigmaP, smuP, swP, serevP,
                                  &inp_lds[0][0], &inp_lds[1][0], c, j);
    red[tid] = make_float4(acc.na0.x + acc.na0.y + acc.nb0.x + acc.nb0.y,
                           acc.da0.x + acc.da0.y + acc.db0.x + acc.db0.y,
                           acc.na1.x + acc.na1.y + acc.nb1.x + acc.nb1.y,
                           acc.da1.x + acc.da1.y + acc.db1.x + acc.db1.y);
  }
  __syncthreads();

  float snum0 = 0.f, sden0 = 0.f, snum1 = 0.f, sden1 = 0.f;
  float cmt0 = 0.f, cmt1 = 0.f, glj = 0.f, glvl = 0.f;
  if (c == 0) {
    float4 a = red[j], b = red[256 + j], cc = red[512 + j], d = red[768 + j];
    snum0 = a.x + b.x + cc.x + d.x;
    sden0 = a.y + b.y + cc.y + d.y;
    snum1 = a.z + b.z + cc.z + d.z;
    sden1 = a.w + b.w + cc.w + d.w;
    glj = gleak[j];
    glvl = glj * vleak[j];
    float cmj = cm[j];
    cmt0 = cmj / ((ts[b0] + 1.f) / (float)UNFOLDS);
    cmt1 = cmj / ((ts[b0 + 1] + 1.f) / (float)UNFOLDS);
  }
  __syncthreads();  // red[] reused by step loop

  // ---- 6 ODE unfolds, v resident in LDS ----
  float vo0 = 0.f, vo1 = 0.f;
  for (int step = 0; step < UNFOLDS; ++step) {
    Acc8 acc = pass_accum<PACKED>(pa, pam, pws, sigmaP, muP, wP, erevP,
                                  &v_lds[0][0], &v_lds[1][0], c, j);
    red[tid] = make_float4(acc.na0.x + acc.na0.y + acc.nb0.x + acc.nb0.y,
                           acc.da0.x + acc.da0.y + acc.db0.x + acc.db0.y,
                           acc.na1.x + acc.na1.y + acc.nb1.x + acc.nb1.y,
                           acc.da1.x + acc.da1.y + acc.db1.x + acc.db1.y);
    __syncthreads();
    if (c == 0) {
      float4 a = red[j], b = red[256 + j], cc = red[512 + j], d = red[768 + j];
      float num0 = a.x + b.x + cc.x + d.x + snum0;
      float den0 = a.y + b.y + cc.y + d.y + sden0;
      float num1 = a.z + b.z + cc.z + d.z + snum1;
      float den1 = a.w + b.w + cc.w + d.w + sden1;
      float v0 = v_lds[0][j], v1 = v_lds[1][j];
      vo0 = (cmt0 * v0 + glvl + num0) / (cmt0 + glj + den0 + EPS);
      vo1 = (cmt1 * v1 + glvl + num1) / (cmt1 + glj + den1 + EPS);
      v_lds[0][j] = vo0;
      v_lds[1][j] = vo1;
    }
    __syncthreads();
  }

  if (c == 0) {
    out[b0 * Nn + j] = vo0;
    out[(b0 + 1) * Nn + j] = vo1;
  }
}

extern "C" void kernel_launch(void* const* d_in, const int* in_sizes, int n_in,
                              void* d_out, int out_size, void* d_ws, size_t ws_size,
                              hipStream_t stream) {
  const float* input   = (const float*)d_in[0];
  const float* hx      = (const float*)d_in[1];
  const float* ts      = (const float*)d_in[2];
  const float* gleak   = (const float*)d_in[3];
  const float* vleak   = (const float*)d_in[4];
  const float* cm      = (const float*)d_in[5];
  const float* sigma   = (const float*)d_in[6];
  const float* mu      = (const float*)d_in[7];
  const float* w       = (const float*)d_in[8];
  const float* erev    = (const float*)d_in[9];
  const float* ssigma  = (const float*)d_in[10];
  const float* smu     = (const float*)d_in[11];
  const float* sw      = (const float*)d_in[12];
  const float* serev   = (const float*)d_in[13];
  const float* input_w = (const float*)d_in[14];
  const float* input_b = (const float*)d_in[15];
  float* out = (float*)d_out;

  const int plane = (Nn / 4) * Nn;                    // 16384 float4
  const size_t need = (size_t)6 * plane * sizeof(float4);  // 1.5 MB
  if (ws_size >= need) {
    float4* pa = (float4*)d_ws;
    float4* pam = pa + plane;
    float4* pws = pam + plane;
    float4* sa = pws + plane;
    float4* sam = sa + plane;
    float4* sws = sam + plane;
    pack_kernel<<<plane / 256, 256, 0, stream>>>(sigma, mu, w, erev, ssigma, smu,
                                                 sw, serev, pa, pam, pws, sa, sam, sws);
    ltc_kernel<true><<<Bb / 2, 1024, 0, stream>>>(
        input, hx, ts, gleak, vleak, cm, input_w, input_b,
        pa, pam, pws, sa, sam, sws,
        sigma, mu, w, erev, ssigma, smu, sw, serev, out);
  } else {
    ltc_kernel<false><<<Bb / 2, 1024, 0, stream>>>(
        input, hx, ts, gleak, vleak, cm, input_w, input_b,
        nullptr, nullptr, nullptr, nullptr, nullptr, nullptr,
        sigma, mu, w, erev, ssigma, smu, sw, serev, out);
  }
}